// Round 5
// baseline (587.627 us; speedup 1.0000x reference)
//
#include <hip/hip_runtime.h>
#include <hip/hip_bf16.h>

#define NN 768
#define NE 24576
#define NPOS 4096
#define NCELL (NN*NN)   // 589824 = 2304*256
#define NBKT 1536       // (row, half) buckets
#define HALFW 384

typedef __hip_bfloat16 bf16;

__device__ __forceinline__ float bf2f(bf16 v) { return __bfloat162float(v); }

// dtype-flexible load: mode==1 -> bf16 storage, mode==0 -> f32 storage
__device__ __forceinline__ float ldf(const void* p, int i, int mode) {
    return mode ? __bfloat162float(((const bf16*)p)[i]) : ((const float*)p)[i];
}

// ---------------- setup: clear cell/aux, detect dtype, convert weights ----------------
__global__ void k_setup(const void* __restrict__ gW, const void* __restrict__ gB,
                        const void* __restrict__ m1W, const void* __restrict__ m1B,
                        const void* __restrict__ m2W, const void* __restrict__ m2B,
                        const void* __restrict__ m3W, const void* __restrict__ m3B,
                        const void* __restrict__ lW,  const void* __restrict__ lB,
                        const void* __restrict__ emb,
                        int* __restrict__ cell, float* __restrict__ stats,
                        int* __restrict__ cursor, int* __restrict__ rowlen,
                        int* __restrict__ rowlo, int* __restrict__ done,
                        int* __restrict__ modeg,
                        float* __restrict__ gwf, float* __restrict__ gbf,
                        float* __restrict__ w1f, float* __restrict__ b1f,
                        float* __restrict__ w2f, float* __restrict__ b2f,
                        float* __restrict__ w3q, float* __restrict__ linf, float* __restrict__ linb) {
    int t = threadIdx.x;
    int b = blockIdx.x;
    if (b < NCELL / 256) { cell[b * 256 + t] = 0; return; }
    if (b == NCELL / 256 + 1) {
        for (int i = t; i < NN; i += 256) { cursor[i] = 0; rowlen[i] = 0; rowlo[i] = 0; }
        if (t < 66) stats[t] = 0.f;
        if (t == 0) *done = 0;
        return;
    }
    // detect dtype then convert weights
    __shared__ int bad;
    if (t == 0) bad = 0;
    __syncthreads();
    int local = 0;
    for (int i = t; i < 3232; i += 256) {
        float a = fabsf(__bfloat162float(((const bf16*)emb)[i]));
        if (!(a < 100.f)) local = 1;
    }
    if (local) atomicOr(&bad, 1);
    __syncthreads();
    int mode = bad ? 0 : 1;
    if (t == 0) *modeg = mode;
    for (int i = t; i < 2048; i += 256) {
        gwf[i] = ldf(gW, i, mode);
        w1f[i] = ldf(m1W, i, mode);
        w2f[i] = ldf(m2W, i, mode);
    }
    for (int i = t; i < 64; i += 256) { gbf[i] = ldf(gB, i, mode); linf[i] = ldf(lW, i, mode); }
    if (t < 32) { b1f[t] = ldf(m1B, t, mode); b2f[t] = ldf(m2B, t, mode); }
    for (int i = t; i < 1056; i += 256) { int c = i >> 5, d = i & 31; w3q[d * 36 + c] = ldf(m3W, i, mode); }
    if (t < 32) { w3q[t * 36 + 33] = ldf(m3B, t, mode); w3q[t * 36 + 34] = 0.f; w3q[t * 36 + 35] = 0.f; }
    if (t == 0) linb[0] = ldf(lB, 0, mode);
}

// ---------------- edge scatter + first-touch rowlen ----------------
__global__ void k_scatter(const int* __restrict__ ei, int* __restrict__ cell, int* __restrict__ rowlen) {
    int e = blockIdx.x * 256 + threadIdx.x;
    if (e < NE) {
        int a = ei[e], b = ei[NE + e];
        if ((unsigned)a < (unsigned)NN && (unsigned)b < (unsigned)NN) {
            int old = atomicAdd(&cell[a * NN + b], 1);
            if (old == 0) atomicAdd(&rowlen[a], 1);
        }
    }
}

// ---------------- scan rows (serial thread 0) + dinv ----------------
__global__ void k_scan(const int* __restrict__ rowlen, int* __restrict__ row_ptr, float* __restrict__ dinv) {
    __shared__ int s[NN];
    __shared__ int ps[NN + 1];
    int t = threadIdx.x;
    for (int i = t; i < NN; i += 256) { s[i] = rowlen[i]; dinv[i] = rsqrtf((float)rowlen[i] + 1.0f); }
    __syncthreads();
    if (t == 0) {
        int a = 0;
        for (int i = 0; i < NN; i++) { ps[i] = a; a += s[i]; }
        ps[NN] = a;
    }
    __syncthreads();
    for (int i = t; i <= NN; i += 256) row_ptr[i] = ps[i];
}

// ---------------- parallel CSR fill; cell -> pairIdx in-place; rowlo counts ----------------
__global__ void k_fillpar(int* __restrict__ cell, const int* __restrict__ row_ptr, int* __restrict__ cursor,
                          int* __restrict__ col_idx, float* __restrict__ cntv, int* __restrict__ pr_row,
                          int* __restrict__ rowlo) {
    int idx = blockIdx.x * 256 + threadIdx.x;
    if (idx >= NCELL) return;
    int i = idx / NN;
    int j = idx - i * NN;
    int cv = cell[idx];
    if (cv > 0) {
        int p = row_ptr[i] + atomicAdd(&cursor[i], 1);
        col_idx[p] = j; cntv[p] = (float)cv; pr_row[p] = i;
        cell[idx] = p;
        if (j < HALFW) atomicAdd(&rowlo[i], 1);
    } else {
        cell[idx] = -1;
    }
}

// ---------------- layer-0: fused emb gather + h @ W0 ----------------
__global__ void k_matw0(const int* __restrict__ x, const void* __restrict__ emb,
                        const int* __restrict__ modep, const float* __restrict__ gwf,
                        float* __restrict__ o) {
    int idx = blockIdx.x * 256 + threadIdx.x;
    int i = idx >> 5, d = idx & 31;
    int mode = *modep;
    int xi = x[i];
    if (xi < 0) xi = 0; if (xi > 100) xi = 100;
    float s = 0.f;
#pragma unroll
    for (int c = 0; c < 32; c++) s += ldf(emb, xi * 32 + c, mode) * gwf[c * 32 + d];
    o[idx] = s;
}

// ---------------- h @ W (layer l) ----------------
__global__ void k_matw(const float* __restrict__ h, const float* __restrict__ gwf, int l, float* __restrict__ o) {
    int idx = blockIdx.x * 256 + threadIdx.x;
    int i = idx >> 5, d = idx & 31;
    const float* W = gwf + l * 1024;
    float s = 0.f;
#pragma unroll
    for (int c = 0; c < 32; c++) s += h[i * 32 + c] * W[c * 32 + d];
    o[idx] = s;
}

// ---------------- An @ hw + b ----------------
__global__ void k_agg(const float* __restrict__ hw, const int* __restrict__ row_ptr,
                      const int* __restrict__ col_idx, const float* __restrict__ dinv,
                      const float* __restrict__ gbf, int l, float* __restrict__ o) {
    int idx = blockIdx.x * 256 + threadIdx.x;
    int i = idx >> 5, d = idx & 31;
    int base = row_ptr[i], len = row_ptr[i + 1] - base;
    float di = dinv[i];
    float acc = di * hw[i * 32 + d];
    for (int t = 0; t < len; t++) {
        int c = col_idx[base + t];
        acc += dinv[c] * hw[c * 32 + d];
    }
    o[idx] = di * acc + gbf[l * 32 + d];
}

// ---------------- graph norm + relu (single block, 1024 threads) ----------------
__global__ void k_norm(const float* __restrict__ in, float* __restrict__ out) {
    __shared__ float red[1024];
    __shared__ float mean[32], rstd[32];
    int t = threadIdx.x, d = t & 31, g = t >> 5;
    float p = 0.f;
    for (int r = g; r < NN; r += 32) p += in[r * 32 + d];
    red[t] = p;
    __syncthreads();
    if (t < 32) { float s = 0.f; for (int k = 0; k < 32; k++) s += red[k * 32 + t]; mean[t] = s / (float)NN; }
    __syncthreads();
    p = 0.f;
    for (int r = g; r < NN; r += 32) { float v = in[r * 32 + d] - mean[d]; p += v * v; }
    red[t] = p;
    __syncthreads();
    if (t < 32) { float s = 0.f; for (int k = 0; k < 32; k++) s += red[k * 32 + t]; rstd[t] = rsqrtf(s / (float)NN + 1e-5f); }
    __syncthreads();
    for (int e = t; e < NN * 32; e += 1024) {
        int dd = e & 31;
        out[e] = fmaxf((in[e] - mean[dd]) * rstd[dd], 0.f);
    }
}

// ---------------- per-distinct-pair MLP1/MLP2, premultiplied by multiplicity ----------------
__global__ void k_edgemlp(const float* __restrict__ h, const int* __restrict__ row_ptr,
                          const int* __restrict__ col_idx, const int* __restrict__ pr_row,
                          const float* __restrict__ cntv,
                          const float* __restrict__ w1f, const float* __restrict__ b1f,
                          const float* __restrict__ w2f, const float* __restrict__ b2f,
                          float* __restrict__ xep, float* __restrict__ mulp) {
    int t = threadIdx.x, d = t & 31;
    int p = blockIdx.x * 8 + (t >> 5);
    if (p >= NE) return;
    if (p >= row_ptr[NN]) { xep[p * 32 + d] = 0.f; mulp[p * 32 + d] = 0.f; return; }
    int i = pr_row[p], j = col_idx[p];
    float a1 = b1f[d], a2 = b2f[d];
#pragma unroll
    for (int c = 0; c < 32; c++) {
        float hv = h[i * 32 + c];
        a1 += hv * w1f[c * 32 + d];
        a2 += hv * w2f[c * 32 + d];
    }
#pragma unroll
    for (int c = 0; c < 32; c++) {
        float hv = h[j * 32 + c];
        a1 += hv * w1f[(32 + c) * 32 + d];
        a2 += hv * w2f[(32 + c) * 32 + d];
    }
    float cv = cntv[p];
    xep[p * 32 + d]  = cv * fmaxf(a1, 0.f);
    mulp[p * 32 + d] = cv * fmaxf(a2, 0.f);
}

// ---------------- path-join prep: bucket counts + scan + zero cursors ----------------
__global__ void k_prep(const int* __restrict__ row_ptr, const int* __restrict__ col_idx,
                       const int* __restrict__ rowlo,
                       int* __restrict__ bptr, int* __restrict__ cur2) {
    __shared__ int pc[NBKT];
    __shared__ int ps[NBKT + 1];
    int t = threadIdx.x;
    for (int b = t; b < NBKT; b += 256) cur2[b] = 0;
    for (int i = t; i < NN; i += 256) {
        int base = row_ptr[i], len = row_ptr[i + 1] - base;
        int lo = 0, tot = 0;
        for (int e = 0; e < len; e++) {
            int k = col_idx[base + e];
            lo += rowlo[k];
            tot += row_ptr[k + 1] - row_ptr[k];
        }
        pc[2 * i] = lo;
        pc[2 * i + 1] = tot - lo;
    }
    __syncthreads();
    if (t == 0) {
        int a = 0;
        for (int b = 0; b < NBKT; b++) { ps[b] = a; a += pc[b]; }
        ps[NBKT] = a;
    }
    __syncthreads();
    for (int b = t; b <= NBKT; b += 256) bptr[b] = ps[b];
}

// ---------------- path-join fill: one thread per e1 edge ----------------
__global__ void k_join(const int* __restrict__ row_ptr, const int* __restrict__ col_idx,
                       const int* __restrict__ pr_row, const int* __restrict__ rowlo,
                       const int* __restrict__ bptr, int* __restrict__ cur2,
                       int2* __restrict__ paths, int cap) {
    int e1 = blockIdx.x * 256 + threadIdx.x;
    if (e1 >= row_ptr[NN]) return;
    int i = pr_row[e1], k = col_idx[e1];
    int kb = row_ptr[k], klen = row_ptr[k + 1] - kb;
    int lo = rowlo[k];
    int s0 = bptr[2 * i]     + atomicAdd(&cur2[2 * i],     lo);
    int s1 = bptr[2 * i + 1] + atomicAdd(&cur2[2 * i + 1], klen - lo);
    for (int e = 0; e < klen; e++) {
        int e2 = kb + e;
        int j = col_idx[e2];
        int slot = (j < HALFW) ? s0++ : s1++;
        if (slot < cap) paths[slot] = make_int2(e1 | (j << 16), e2);
    }
}

// ---------------- fused: path-scatter into LDS C-tile + z + masked stats ----------------
__global__ __launch_bounds__(256) void k_big(const int* __restrict__ bptr, const int2* __restrict__ paths,
                                             const int* __restrict__ cell,
                                             const float* __restrict__ xep, const float* __restrict__ mulp,
                                             const float* __restrict__ w3q,
                                             float* __restrict__ stats, int* __restrict__ done,
                                             float* __restrict__ nrm, int cap) {
    __shared__ float Cs[HALFW * 32];        // 48 KB, swizzled: [jj*32 + ((d+jj)&31)]
    __shared__ int   mk[HALFW];
    __shared__ float sS1[32], sS2[32], sCm[32];
    __shared__ int amlast;
    int t = threadIdx.x, d = t & 31, tt = t >> 5;
    int bkt = blockIdx.x;
    int i = bkt >> 1;
    int jbase = (bkt & 1) * HALFW;
    // clear
    for (int e = t; e < HALFW * 32; e += 256) Cs[e] = 0.f;
    for (int e = t; e < HALFW; e += 256) mk[e] = 0;
    if (t < 32) { sS1[t] = 0.f; sS2[t] = 0.f; sCm[t] = 0.f; }
    __syncthreads();
    // phase A: flat path scatter (independent iterations, coalesced streams)
    int pstart = bptr[bkt], pend = bptr[bkt + 1];
    if (pend > cap) pend = cap;
    for (int p = pstart + tt; p < pend; p += 8) {
        int2 rec = paths[p];
        int e1 = rec.x & 0xFFFF;
        int j  = ((unsigned)rec.x) >> 16;
        int e2 = rec.y;
        int jj = j - jbase;
        float v = xep[e1 * 32 + d] * mulp[e2 * 32 + d];
        atomicAdd(&Cs[jj * 32 + ((d + jj) & 31)], v);
        if (d == 0) mk[jj] = 1;
    }
    __syncthreads();
    // phase B: per-cell z + stats
    float ts1[32], ts2[32];
#pragma unroll
    for (int c = 0; c < 32; c++) { ts1[c] = 0.f; ts2[c] = 0.f; }
    float cm = 0.f;
    for (int rep = 0; rep < 2; rep++) {
        int jj = rep * 256 + t;
        if (jj >= HALFW) break;
        float Creg[32];
#pragma unroll
        for (int c = 0; c < 32; c++) Creg[c] = Cs[jj * 32 + ((c + jj) & 31)];
        bool adj = cell[i * NN + jbase + jj] >= 0;
        float af = adj ? 1.f : 0.f;
        float msk = (mk[jj] || adj) ? 1.f : 0.f;
        cm += msk;
#pragma unroll
        for (int dd = 0; dd < 32; dd++) {
            const float4* wr = (const float4*)(w3q + dd * 36);   // thread-uniform -> scalar loads
            float4 wv = wr[8];                                   // x = ind weight, y = b3
            float z = wv.y + af * wv.x;
            wv = wr[0]; z += Creg[0]*wv.x + Creg[1]*wv.y + Creg[2]*wv.z + Creg[3]*wv.w;
            wv = wr[1]; z += Creg[4]*wv.x + Creg[5]*wv.y + Creg[6]*wv.z + Creg[7]*wv.w;
            wv = wr[2]; z += Creg[8]*wv.x + Creg[9]*wv.y + Creg[10]*wv.z + Creg[11]*wv.w;
            wv = wr[3]; z += Creg[12]*wv.x + Creg[13]*wv.y + Creg[14]*wv.z + Creg[15]*wv.w;
            wv = wr[4]; z += Creg[16]*wv.x + Creg[17]*wv.y + Creg[18]*wv.z + Creg[19]*wv.w;
            wv = wr[5]; z += Creg[20]*wv.x + Creg[21]*wv.y + Creg[22]*wv.z + Creg[23]*wv.w;
            wv = wr[6]; z += Creg[24]*wv.x + Creg[25]*wv.y + Creg[26]*wv.z + Creg[27]*wv.w;
            wv = wr[7]; z += Creg[28]*wv.x + Creg[29]*wv.y + Creg[30]*wv.z + Creg[31]*wv.w;
            ts1[dd] += msk * z;
            ts2[dd] += msk * z * z;
        }
    }
    // staggered LDS atomics (conflict-free: lane c+t pattern)
#pragma unroll
    for (int c = 0; c < 32; c++) {
        int dd = (c + t) & 31;
        atomicAdd(&sS1[dd], ts1[dd]);
        atomicAdd(&sS2[dd], ts2[dd]);
    }
    atomicAdd(&sCm[t & 31], cm);
    __syncthreads();
    if (t < 32) {
        atomicAdd(&stats[t], sS1[t]);
        atomicAdd(&stats[32 + t], sS2[t]);
    }
    if (t == 32) {
        float s = 0.f;
        for (int k = 0; k < 32; k++) s += sCm[k];
        atomicAdd(&stats[64], s);
    }
    __syncthreads();
    if (t == 0) {
        __threadfence();
        amlast = (atomicAdd(done, 1) == NBKT - 1) ? 1 : 0;
    }
    __syncthreads();
    if (amlast && t < 32) {
        float sum1 = atomicAdd(&stats[t], 0.f);
        float sum2 = atomicAdd(&stats[32 + t], 0.f);
        float cmv  = atomicAdd(&stats[64], 0.f);
        if (cmv < 1.f) cmv = 1.f;
        float mean = sum1 / cmv;
        float var = sum2 / cmv - mean * mean;
        nrm[t] = mean;
        nrm[32 + t] = rsqrtf(fmaxf(var, 0.f) + 1e-5f);
    }
}

// ---------------- output: recompute C at pos pairs, norm, sym, linear ----------------
__global__ void k_out(const int* __restrict__ pos, const int* __restrict__ row_ptr,
                      const int* __restrict__ col_idx, const int* __restrict__ cell,
                      const float* __restrict__ xep, const float* __restrict__ mulp,
                      const float* __restrict__ h,
                      const float* __restrict__ w3q,
                      const float* __restrict__ nrm,
                      const float* __restrict__ linf, const float* __restrict__ linb,
                      const int* __restrict__ modep, void* __restrict__ outp) {
    __shared__ float Cb[4][2][32];
    int t = threadIdx.x;
    int w = t >> 6, lane = t & 63, d = lane & 31, dir = lane >> 5;
    int p = blockIdx.x * 4 + w;
    int a = pos[2 * p], b = pos[2 * p + 1];
    if ((unsigned)a >= (unsigned)NN) a = 0;
    if ((unsigned)b >= (unsigned)NN) b = 0;
    int r = dir ? b : a;
    int cc = dir ? a : b;
    int base = row_ptr[r], len = row_ptr[r + 1] - base;
    float acc = 0.f;
    bool hit = false;
    for (int tt = 0; tt < len; tt++) {
        int e1 = base + tt;
        int k = col_idx[e1];
        int e2 = cell[k * NN + cc];
        if (e2 >= 0) { hit = true; acc += xep[e1 * 32 + d] * mulp[e2 * 32 + d]; }
    }
    Cb[w][dir][d] = acc;
    bool adj = cell[r * NN + cc] >= 0;
    float msk = (hit || adj) ? 1.f : 0.f;
    __syncthreads();
    float z = w3q[d * 36 + 33] + (adj ? 1.f : 0.f) * w3q[d * 36 + 32];
#pragma unroll
    for (int c = 0; c < 32; c++) z += Cb[w][dir][c] * w3q[d * 36 + c];
    float zn = fmaxf((z - nrm[d]) * nrm[32 + d], 0.f);
    float zp = __shfl_xor(zn, 32);
    float symd = msk * zn * zp;
    float xxd = h[a * 32 + d] * h[b * 32 + d];
    float contrib = symd * linf[d] + xxd * linf[32 + d];
    for (int off = 16; off >= 1; off >>= 1) contrib += __shfl_xor(contrib, off);
    if (lane == 0) {
        float v = contrib + linb[0];
        v = fminf(fmaxf(v, -1e4f), 1e4f);
        if (*modep) ((bf16*)outp)[p] = __float2bfloat16(v);
        else        ((float*)outp)[p] = v;
    }
}

extern "C" void kernel_launch(void* const* d_in, const int* in_sizes, int n_in,
                              void* d_out, int out_size, void* d_ws, size_t ws_size,
                              hipStream_t stream) {
    const void* px  = d_in[0];  const void* pei = d_in[1];  const void* ppos = d_in[2];
    const void* pemb = d_in[3]; const void* pgW = d_in[4];  const void* pgB  = d_in[5];
    const void* pm1W = d_in[6]; const void* pm1B = d_in[7]; const void* pm2W = d_in[8];
    const void* pm2B = d_in[9]; const void* pm3W = d_in[10]; const void* pm3B = d_in[11];
    const void* plW = d_in[12]; const void* plB = d_in[13];
    {
        int c2048 = 0, c64 = 0, c32 = 0;
        for (int i = 0; i < n_in; i++) {
            int s = in_sizes[i]; const void* p = d_in[i];
            switch (s) {
                case 768:   px = p; break;
                case 49152: pei = p; break;
                case 8192:  ppos = p; break;
                case 3232:  pemb = p; break;
                case 2048:  if (c2048 == 0) pgW = p; else if (c2048 == 1) pm1W = p; else pm2W = p; c2048++; break;
                case 64:    if (c64 == 0) pgB = p; else plW = p; c64++; break;
                case 32:    if (c32 == 0) pm1B = p; else if (c32 == 1) pm2B = p; else pm3B = p; c32++; break;
                case 1056:  pm3W = p; break;
                case 1:     plB = p; break;
                default: break;
            }
        }
    }

    char* ws = (char*)d_ws;
    size_t off = 0;
    auto alloc = [&](size_t bytes) -> void* {
        void* pp = ws + off;
        off += (bytes + 255) & ~(size_t)255;
        return pp;
    };
    int*   cell    = (int*)alloc(NCELL * 4);
    int*   rowlen  = (int*)alloc(NN * 4);
    int*   rowlo   = (int*)alloc(NN * 4);
    int*   row_ptr = (int*)alloc((NN + 1) * 4);
    int*   col_idx = (int*)alloc(NE * 4);
    float* cntv    = (float*)alloc(NE * 4);
    int*   pr_row  = (int*)alloc(NE * 4);
    int*   cursor  = (int*)alloc(NN * 4);
    float* dinv    = (float*)alloc(NN * 4);
    float* h       = (float*)alloc(NN * 32 * 4);
    float* bufA    = (float*)alloc(NN * 32 * 4);
    float* bufB    = (float*)alloc(NN * 32 * 4);
    float* xep     = (float*)alloc(NE * 32 * 4);
    float* mulp    = (float*)alloc(NE * 32 * 4);
    float* stats   = (float*)alloc(66 * 4);
    float* nrm     = (float*)alloc(64 * 4);
    float* gwf     = (float*)alloc(2048 * 4);
    float* gbf     = (float*)alloc(64 * 4);
    float* w1f     = (float*)alloc(2048 * 4);
    float* b1f     = (float*)alloc(32 * 4);
    float* w2f     = (float*)alloc(2048 * 4);
    float* b2f     = (float*)alloc(32 * 4);
    float* w3q     = (float*)alloc(32 * 36 * 4);
    float* linf    = (float*)alloc(64 * 4);
    float* linb    = (float*)alloc(4);
    int*   mode    = (int*)alloc(4);
    int*   done    = (int*)alloc(4);
    int*   bptr    = (int*)alloc((NBKT + 1) * 4);
    int*   cur2    = (int*)alloc(NBKT * 4);
    // paths last: use remaining workspace, capped at 1M records
    size_t remain = (ws_size > off) ? (ws_size - off) : 0;
    int cap = (int)(remain / 8);
    if (cap > (1 << 20)) cap = (1 << 20);
    int2*  paths   = (int2*)alloc((size_t)cap * 8);

    k_setup<<<NCELL / 256 + 2, 256, 0, stream>>>(pgW, pgB, pm1W, pm1B, pm2W, pm2B, pm3W, pm3B, plW, plB,
                                                 pemb, cell, stats, cursor, rowlen, rowlo, done, mode,
                                                 gwf, gbf, w1f, b1f, w2f, b2f, w3q, linf, linb);
    k_scatter<<<NE / 256, 256, 0, stream>>>((const int*)pei, cell, rowlen);
    k_scan<<<1, 256, 0, stream>>>(rowlen, row_ptr, dinv);
    k_fillpar<<<NCELL / 256, 256, 0, stream>>>(cell, row_ptr, cursor, col_idx, cntv, pr_row, rowlo);
    k_matw0<<<NN * 32 / 256, 256, 0, stream>>>((const int*)px, pemb, mode, gwf, bufA);
    k_agg<<<NN * 32 / 256, 256, 0, stream>>>(bufA, row_ptr, col_idx, dinv, gbf, 0, bufB);
    k_norm<<<1, 1024, 0, stream>>>(bufB, h);
    k_matw<<<NN * 32 / 256, 256, 0, stream>>>(h, gwf, 1, bufA);
    k_agg<<<NN * 32 / 256, 256, 0, stream>>>(bufA, row_ptr, col_idx, dinv, gbf, 1, bufB);
    k_norm<<<1, 1024, 0, stream>>>(bufB, h);
    k_prep<<<1, 256, 0, stream>>>(row_ptr, col_idx, rowlo, bptr, cur2);
    k_join<<<NE / 256, 256, 0, stream>>>(row_ptr, col_idx, pr_row, rowlo, bptr, cur2, paths, cap);
    k_edgemlp<<<NE / 8, 256, 0, stream>>>(h, row_ptr, col_idx, pr_row, cntv, w1f, b1f, w2f, b2f, xep, mulp);
    k_big<<<NBKT, 256, 0, stream>>>(bptr, paths, cell, xep, mulp, w3q, stats, done, nrm, cap);
    k_out<<<NPOS / 4, 256, 0, stream>>>((const int*)ppos, row_ptr, col_idx, cell, xep, mulp, h,
                                        w3q, nrm, linf, linb, mode, d_out);
}